// Round 4
// baseline (347.730 us; speedup 1.0000x reference)
//
#include <hip/hip_runtime.h>

#define DHW   192
#define R     8
#define NPTS  16

// ---------------------------------------------------------------------------
// Zero-fill via the runtime's memset path (graph-capturable memset node →
// rocclr fillBuffer, measured at 6.1 TB/s on this chip — 2x what any of our
// hand-rolled store kernels achieved). Then paint the 64 Gaussian cubes
// (~1.3 MB of writes) with a tiny kernel.
// ---------------------------------------------------------------------------

// One block per (batch, point). Last-writer-wins per (channel, voxel): point j
// writes a voxel only if no later point j' > j on the same channel covers it
// (reference's sequential dynamic_update_slice semantics — including zeroed
// kernel corners, r2 >= 128, which DO overwrite earlier values).
// Verified correct (absmax 0.0) in round 2.
__global__ __launch_bounds__(256) void paint_kernel(
    const float* __restrict__ coords,   // (4,16,3) float32: x,y,z
    const int*   __restrict__ labels,   // (4,16) int32 in {-1,0,1}
    float*       __restrict__ out)
{
    const int b = blockIdx.x / NPTS;
    const int j = blockIdx.x % NPTS;
    const int lab = labels[b * NPTS + j];
    if (lab != 0 && lab != 1) return;   // l == -1 writes nothing

    const int px = (int)coords[(b * NPTS + j) * 3 + 0];
    const int py = (int)coords[(b * NPTS + j) * 3 + 1];
    const int pz = (int)coords[(b * NPTS + j) * 3 + 2];

    // Later points of this batch on the SAME channel (shared mem so indexing
    // stays static — per-thread runtime-indexed arrays would spill).
    __shared__ int slx[NPTS], sly[NPTS], slz[NPTS];
    __shared__ int snl;
    if (threadIdx.x == 0) {
        int nl = 0;
        for (int j2 = j + 1; j2 < NPTS; ++j2) {
            if (labels[b * NPTS + j2] == lab) {
                slx[nl] = (int)coords[(b * NPTS + j2) * 3 + 0];
                sly[nl] = (int)coords[(b * NPTS + j2) * 3 + 1];
                slz[nl] = (int)coords[(b * NPTS + j2) * 3 + 2];
                ++nl;
            }
        }
        snl = nl;
    }
    __syncthreads();
    const int nl = snl;

    const int ch = (lab == 1) ? 0 : 1;  // pos channel, then neg
    const size_t vol = (size_t)DHW * DHW * DHW;
    float* __restrict__ dst = out + (size_t)(b * 2 + ch) * vol;

    for (int t = threadIdx.x; t < 17 * 17 * 17; t += 256) {
        const int dz  = t / 289;            // 289 = 17*17
        const int rem = t - dz * 289;
        const int dy  = rem / 17;
        const int dx  = rem - dy * 17;
        const int z = pz + dz - R;          // unpadded (cropped) coords
        const int y = py + dy - R;
        const int x = px + dx - R;
        if ((unsigned)z >= DHW || (unsigned)y >= DHW || (unsigned)x >= DHW)
            continue;                       // pad region -> cropped away
        bool stolen = false;
        for (int k = 0; k < nl; ++k) {
            if (abs(z - slz[k]) <= R && abs(y - sly[k]) <= R &&
                abs(x - slx[k]) <= R) { stolen = true; break; }
        }
        if (stolen) continue;               // a later point rewrites this voxel
        const int rz = dz - R, ry = dy - R, rx = dx - R;
        const int r2 = rz * rz + ry * ry + rx * rx;
        // reference zeroes entries with h < eps*h.max()  <=>  r2 >= 128
        const float v = (r2 >= 128) ? 0.f : __expf((float)r2 * -0.125f);
        dst[((size_t)z * DHW + y) * DHW + x] = v;
    }
}

extern "C" void kernel_launch(void* const* d_in, const int* in_sizes, int n_in,
                              void* d_out, int out_size, void* d_ws, size_t ws_size,
                              hipStream_t stream) {
    const float* coords = (const float*)d_in[0];  // 4*16*3 floats
    const int*   labels = (const int*)d_in[1];    // 4*16 ints
    float*       out    = (float*)d_out;          // 12*192^3 floats

    const size_t nbytes = (size_t)12 * DHW * DHW * DHW * sizeof(float);
    // Runtime fill path (graph memset node): 6.1 TB/s measured on this chip.
    hipMemsetAsync(out, 0, nbytes, stream);
    paint_kernel<<<4 * NPTS, 256, 0, stream>>>(coords, labels, out);
}